// Round 10
// baseline (184.631 us; speedup 1.0000x reference)
//
#include <hip/hip_runtime.h>
#include <hip/hip_bf16.h>
#include <cstdint>
#include <cstddef>

typedef __bf16 bf16_t;
typedef __bf16 bf16x4 __attribute__((ext_vector_type(4)));
typedef __bf16 bf16x8 __attribute__((ext_vector_type(8)));
typedef float  f32x4  __attribute__((ext_vector_type(4)));
typedef float  f32x16 __attribute__((ext_vector_type(16)));
typedef unsigned int u32;
typedef unsigned int u32x4 __attribute__((ext_vector_type(4)));

#define DIM_   1024
#define HEADS_ 16
#define HD_    64
#define BB_    2
#define NN_    2048
#define MTOT   (BB_*NN_)
static constexpr float SCALE_ = 0.03125f;              // 1/sqrt(1024)
static constexpr float EXPC_  = 0.045084220027780106f; // SCALE * log2(e), folded into q-proj

// ---------------------------------------------------------------------------
// fp32 -> bf16 bulk convert, all 5 arrays in one launch.
// blocks 0..2047: x (4M elems). blocks 2048..4095: Wq/Wk/Wv/Wo (1M each).
// ---------------------------------------------------------------------------
__global__ __launch_bounds__(256) void cvt_all(
    const float* __restrict__ X,
    const float* __restrict__ W0, const float* __restrict__ W1,
    const float* __restrict__ W2, const float* __restrict__ W3,
    bf16_t* __restrict__ xo,
    bf16_t* __restrict__ o0, bf16_t* __restrict__ o1,
    bf16_t* __restrict__ o2, bf16_t* __restrict__ o3)
{
    const int bid = blockIdx.x;
    const float* src;
    bf16_t* dst;
    int lb;
    if (bid < 2048) { src = X; dst = xo; lb = bid; }
    else {
        const int w = (bid - 2048) >> 9;
        lb = (bid - 2048) & 511;
        src = (w == 0) ? W0 : (w == 1) ? W1 : (w == 2) ? W2 : W3;
        dst = (w == 0) ? o0 : (w == 1) ? o1 : (w == 2) ? o2 : o3;
    }
    const size_t i = ((size_t)lb * 256 + threadIdx.x) * 8;
    f32x4 a = *(const f32x4*)(src + i);
    f32x4 b = *(const f32x4*)(src + i + 4);
    bf16x8 o;
    o[0] = (bf16_t)a.x; o[1] = (bf16_t)a.y; o[2] = (bf16_t)a.z; o[3] = (bf16_t)a.w;
    o[4] = (bf16_t)b.x; o[5] = (bf16_t)b.y; o[6] = (bf16_t)b.z; o[7] = (bf16_t)b.w;
    *(bf16x8*)(dst + i) = o;
}

// ---------------------------------------------------------------------------
// gemm_bb: C = (A(bf16) @ Wb(bf16)^T + bias) * osc.  m97 structure. (verified)
// ---------------------------------------------------------------------------
__device__ __forceinline__ void gld16(const bf16_t* g, bf16_t* l) {
    __builtin_amdgcn_global_load_lds(
        (const __attribute__((address_space(1))) unsigned int*)g,
        (__attribute__((address_space(3))) unsigned int*)l, 16, 0, 0);
}

template<bool CBF>
__global__ __launch_bounds__(256) void gemm_bb(
    const bf16_t* __restrict__ A,
    const bf16_t* __restrict__ W0, const bf16_t* __restrict__ W1, const bf16_t* __restrict__ W2,
    const float* __restrict__ B0, const float* __restrict__ B1, const float* __restrict__ B2,
    void* __restrict__ C0, void* __restrict__ C1, void* __restrict__ C2,
    float s0, float s1, float s2,
    int M, int N, int K)
{
    const bf16_t* Wt  = (blockIdx.z == 0) ? W0 : (blockIdx.z == 1 ? W1 : W2);
    const float* bias = (blockIdx.z == 0) ? B0 : (blockIdx.z == 1 ? B1 : B2);
    void*        Cp   = (blockIdx.z == 0) ? C0 : (blockIdx.z == 1 ? C1 : C2);
    const float  osc  = (blockIdx.z == 0) ? s0 : (blockIdx.z == 1 ? s1 : s2);

    __shared__ __align__(16) bf16_t As[128 * 64];
    __shared__ __align__(16) bf16_t Bs[128 * 64];

    const int tid  = threadIdx.x;
    const int lane = tid & 63;
    const int wave = tid >> 6;
    const int wr   = wave >> 1;
    const int wc   = wave & 1;
    const int bm   = blockIdx.y, bn = blockIdx.x;

    const int l15 = lane & 15;
    const int g   = lane >> 4;

    const int grow = lane >> 3;
    const int gcol = (lane & 7) * 8;

    f32x4 acc[4][4];
    #pragma unroll
    for (int i = 0; i < 4; i++)
        #pragma unroll
        for (int j = 0; j < 4; j++)
            acc[i][j] = (f32x4){0.f, 0.f, 0.f, 0.f};

    for (int kb = 0; kb < K; kb += 64) {
        __syncthreads();
        #pragma unroll
        for (int i = 0; i < 4; i++) {
            const int r0 = i * 32 + wave * 8;
            gld16(A  + (size_t)(bm * 128 + r0 + grow) * K + kb + gcol, As + r0 * 64);
            gld16(Wt + (size_t)(bn * 128 + r0 + grow) * K + kb + gcol, Bs + r0 * 64);
        }
        __syncthreads();

        #pragma unroll
        for (int kk = 0; kk < 2; kk++) {
            bf16x8 af[4], bfr[4];
            #pragma unroll
            for (int i = 0; i < 4; i++) {
                af[i]  = *(const bf16x8*)&As[(wr * 64 + i * 16 + l15) * 64 + kk * 32 + g * 8];
                bfr[i] = *(const bf16x8*)&Bs[(wc * 64 + i * 16 + l15) * 64 + kk * 32 + g * 8];
            }
            #pragma unroll
            for (int i = 0; i < 4; i++)
                #pragma unroll
                for (int j = 0; j < 4; j++)
                    acc[i][j] = __builtin_amdgcn_mfma_f32_16x16x32_bf16(af[i], bfr[j], acc[i][j], 0, 0, 0);
        }
    }

    const int r4 = (lane >> 4) * 4;
    #pragma unroll
    for (int j = 0; j < 4; j++) {
        const int gc = bn * 128 + wc * 64 + j * 16 + l15;
        const float bv = bias[gc];
        #pragma unroll
        for (int i = 0; i < 4; i++) {
            #pragma unroll
            for (int r = 0; r < 4; r++) {
                const int gr = bm * 128 + wr * 64 + i * 16 + r4 + r;
                const float val = (acc[i][j][r] + bv) * osc;
                if (CBF) ((bf16_t*)Cp)[(size_t)gr * N + gc] = (bf16_t)val;
                else     ((float*)Cp)[(size_t)gr * N + gc]  = val;
            }
        }
    }
}

// ---------------------------------------------------------------------------
// Per-head transpose: V[b][m][h*64+d] -> Vt[(b*16+h)*64 + d][m]
// ---------------------------------------------------------------------------
__global__ __launch_bounds__(256) void transpose_v(
    const bf16_t* __restrict__ V, bf16_t* __restrict__ Vt)
{
    __shared__ __align__(16) bf16_t Ts[64 * 72];
    const int tid = threadIdx.x;
    const int mt  = blockIdx.x;
    const int bh  = blockIdx.y;
    const int b   = bh >> 4, h = bh & 15;
    const int m0  = mt * 64;
    const int r   = tid >> 2;
    const int c   = (tid & 3) * 16;

    const bf16x8* s = (const bf16x8*)(V + ((size_t)(b * NN_ + m0 + r)) * DIM_ + h * HD_ + c);
    *(bf16x8*)(Ts + r * 72 + c)     = s[0];
    *(bf16x8*)(Ts + r * 72 + c + 8) = s[1];
    __syncthreads();

    bf16x8 o0, o1;
    #pragma unroll
    for (int i = 0; i < 8; i++) o0[i] = Ts[(c + i) * 72 + r];
    #pragma unroll
    for (int i = 0; i < 8; i++) o1[i] = Ts[(c + 8 + i) * 72 + r];
    bf16_t* dst = Vt + ((size_t)bh * HD_ + r) * NN_ + m0 + c;
    *(bf16x8*)dst       = o0;
    *(bf16x8*)(dst + 8) = o1;
}

// ---------------------------------------------------------------------------
// MFMA attention v8: KVBLK=64 double-buffered (36.9KB LDS), 8 waves
// (4 n-strips x 2 m-halves of 32), scalar VALU L (no oL MFMA).
// ---------------------------------------------------------------------------
__device__ __forceinline__ u32 cvtpk_bf16(float lo, float hi) {
    u32 d;
    asm volatile("v_cvt_pk_bf16_f32 %0, %1, %2" : "=v"(d) : "v"(lo), "v"(hi));
    return d;
}

__global__ __launch_bounds__(512, 6) void attn_mfma8(
    const bf16_t* __restrict__ Qa,   // kb (attention-query rows n)
    const bf16_t* __restrict__ Ka,   // qb (attention-key rows m, pre-scaled by EXPC_)
    const bf16_t* __restrict__ Vtg,  // V^T per head [bh][d][m]
    bf16_t* __restrict__ O)
{
    // S[0..1] = K tiles (dbuf), S[2..3] = V^T tiles (dbuf); 4*64*72*2B = 36.9KB
    __shared__ __align__(16) bf16_t S[4][64 * 72];

    const int tid  = threadIdx.x;
    const int lane = tid & 63;
    const int w    = tid >> 6;       // 0..7
    const int l31  = lane & 31;
    const int h5   = lane >> 5;

    const int nw = (w & 3) * 32;     // wave's n-offset in block
    const int mo = (w >> 2) * 32;    // wave's m-half within each 64-m tile

    // XCD-chunked swizzle: 512 blocks, 64 consecutive ids per XCD
    const int wg = blockIdx.x;
    const int id = (wg & 7) * 64 + (wg >> 3);
    const int bh = id >> 4;          // 0..31
    const int nt = id & 15;          // 0..15
    const int b  = bh >> 4, h = bh & 15;
    const int n0 = nt * 128;

    const size_t base = (size_t)b * NN_ * DIM_ + h * HD_;

    // Q-fragments (B-operand, n = n0 + nw + l31) straight from global
    const bf16_t* qrow = Qa + base + (size_t)(n0 + nw + l31) * DIM_ + h5 * 8;
    bf16x8 qf[4];
    #pragma unroll
    for (int ks = 0; ks < 4; ks++)
        qf[ks] = *(const bf16x8*)(qrow + ks * 16);

    f32x16 oa0 = {}, oa1 = {};
    float Lp = 0.f;

    const bf16_t* vrow   = Vtg + (size_t)bh * HD_ * NN_;
    const bf16_t* kgbase = Ka + base;

    // staging (512 threads, 64x64 tiles): 1 b128 each for K and V^T
    const int sr3 = tid >> 3;          // 0..63
    const int sc3 = (tid & 7) * 8;     // 0..56

    bf16x8 kA0, vA0;

    #define ISSUE(m0v)                                                              \
        {                                                                           \
            kA0 = *(const bf16x8*)(kgbase + (size_t)((m0v) + sr3) * DIM_ + sc3);    \
            vA0 = *(const bf16x8*)(vrow + (size_t)sr3 * NN_ + (m0v) + sc3);         \
        }
    #define COMMIT(buf)                                                             \
        {                                                                           \
            *(bf16x8*)(S[buf] + sr3 * 72 + sc3)     = kA0;                          \
            *(bf16x8*)(S[2 + buf] + sr3 * 72 + sc3) = vA0;                          \
        }

    ISSUE(0);
    COMMIT(0);
    __syncthreads();

    for (int mt = 0; mt < NN_ / 64; mt++) {
        const int cur = mt & 1;
        if (mt < NN_ / 64 - 1) ISSUE((mt + 1) * 64);

        const bf16_t* KtC = S[cur];
        const bf16_t* VtC = S[2 + cur];

        // S^T for this wave's 32-m slice: lane holds 16 P-vals for n = nw + l31
        f32x16 sa = {};
        __builtin_amdgcn_s_setprio(1);
        #pragma unroll
        for (int ks = 0; ks < 4; ks++) {
            bf16x8 kf = *(const bf16x8*)&KtC[(mo + l31) * 72 + ks * 16 + h5 * 8];
            sa = __builtin_amdgcn_mfma_f32_32x32x16_bf16(kf, qf[ks], sa, 0, 0, 0);
        }
        __builtin_amdgcn_s_setprio(0);

        // P = exp2(S^T); scalar L partial (lane-local: all p are same n)
        float p[16];
        #pragma unroll
        for (int r = 0; r < 16; r++) p[r] = exp2f(sa[r]);
        {
            float s0 = (p[0] + p[1]) + (p[2] + p[3]);
            float s1 = (p[4] + p[5]) + (p[6] + p[7]);
            float s2 = (p[8] + p[9]) + (p[10] + p[11]);
            float s3 = (p[12] + p[13]) + (p[14] + p[15]);
            Lp += (s0 + s1) + (s2 + s3);
        }

        // PV A-fragments in-register: 8 cvt_pk + 4 permlane32_swap
        bf16x8 pf[2];
        #pragma unroll
        for (int mb = 0; mb < 2; mb++) {
            const int rb = mb * 8;
            u32 x0 = cvtpk_bf16(p[rb + 0], p[rb + 1]);
            u32 x1 = cvtpk_bf16(p[rb + 2], p[rb + 3]);
            u32 y0 = cvtpk_bf16(p[rb + 4], p[rb + 5]);
            u32 y1 = cvtpk_bf16(p[rb + 6], p[rb + 7]);
            asm volatile("v_permlane32_swap_b32 %0, %1" : "+v"(x0), "+v"(y0));
            asm volatile("v_permlane32_swap_b32 %0, %1" : "+v"(x1), "+v"(y1));
            u32x4 t; t.x = x0; t.y = x1; t.z = y0; t.w = y1;
            pf[mb] = __builtin_bit_cast(bf16x8, t);
        }

        // O += P·V over this wave's 32-m slice
        __builtin_amdgcn_s_setprio(1);
        #pragma unroll
        for (int ms = 0; ms < 2; ms++) {
            bf16x8 vf0 = *(const bf16x8*)&VtC[l31 * 72 + mo + ms * 16 + h5 * 8];
            bf16x8 vf1 = *(const bf16x8*)&VtC[(32 + l31) * 72 + mo + ms * 16 + h5 * 8];
            oa0 = __builtin_amdgcn_mfma_f32_32x32x16_bf16(pf[ms], vf0, oa0, 0, 0, 0);
            oa1 = __builtin_amdgcn_mfma_f32_32x32x16_bf16(pf[ms], vf1, oa1, 0, 0, 0);
        }
        __builtin_amdgcn_s_setprio(0);

        if (mt < NN_ / 64 - 1) COMMIT(cur ^ 1);
        __syncthreads();
    }
    #undef ISSUE
    #undef COMMIT

    // complete lane's L over its 32-m slice (other h5 subset)
    Lp += __shfl_xor(Lp, 32);

    // merge m-half partials (wave w+4 -> wave w), 2 rounds in 36.9KB scratch.
    // slot s: floats [s*2112, s*2112+2112): oa0 1024 | oa1 1024 | L 64
    float* scratch = (float*)S;
    {
        const int s3 = w - 4;   // 0..3 for writers
        if (w >= 4 && w < 7) {
            float* buf = scratch + s3 * 2112;
            #pragma unroll
            for (int reg = 0; reg < 16; reg++) {
                buf[reg * 64 + lane]        = oa0[reg];
                buf[1024 + reg * 64 + lane] = oa1[reg];
            }
            buf[2048 + lane] = Lp;
        }
        __syncthreads();
        if (w < 3) {
            const float* buf = scratch + w * 2112;
            #pragma unroll
            for (int reg = 0; reg < 16; reg++) {
                oa0[reg] += buf[reg * 64 + lane];
                oa1[reg] += buf[1024 + reg * 64 + lane];
            }
            Lp += buf[2048 + lane];
        }
        __syncthreads();
        if (w == 7) {
            float* buf = scratch;
            #pragma unroll
            for (int reg = 0; reg < 16; reg++) {
                buf[reg * 64 + lane]        = oa0[reg];
                buf[1024 + reg * 64 + lane] = oa1[reg];
            }
            buf[2048 + lane] = Lp;
        }
        __syncthreads();
        if (w == 3) {
            const float* buf = scratch;
            #pragma unroll
            for (int reg = 0; reg < 16; reg++) {
                oa0[reg] += buf[reg * 64 + lane];
                oa1[reg] += buf[1024 + reg * 64 + lane];
            }
            Lp += buf[2048 + lane];
        }
        __syncthreads();
    }

    // publish L[n] (lane l31 holds L for n = nw + l31), then epilogue
    float* Lsh = scratch + 8448;   // floats 8448..8575 (block n 0..127)
    if (w < 4) Lsh[nw + l31] = Lp;
    __syncthreads();

    if (w < 4) {
        #pragma unroll
        for (int reg = 0; reg < 16; reg++) {
            const int nr = (reg & 3) + 8 * (reg >> 2) + 4 * h5;
            const float il = 1.f / Lsh[nw + nr];
            const size_t rowoff = base + (size_t)(n0 + nw + nr) * DIM_;
            O[rowoff + l31]      = (bf16_t)(oa0[reg] * il);
            O[rowoff + 32 + l31] = (bf16_t)(oa1[reg] * il);
        }
    }
}

// ---------------------------------------------------------------------------
extern "C" void kernel_launch(void* const* d_in, const int* in_sizes, int n_in,
                              void* d_out, int out_size, void* d_ws, size_t ws_size,
                              hipStream_t stream)
{
    const float* x  = (const float*)d_in[0];
    const float* Wq = (const float*)d_in[1];
    const float* bq = (const float*)d_in[2];
    const float* Wk = (const float*)d_in[3];
    const float* bk = (const float*)d_in[4];
    const float* Wv = (const float*)d_in[5];
    const float* bv = (const float*)d_in[6];
    const float* Wo = (const float*)d_in[7];
    const float* bo = (const float*)d_in[8];
    float* out = (float*)d_out;

    const size_t SEG = (size_t)MTOT * DIM_;   // 4M elems = 8MB bf16
    bf16_t* xb = (bf16_t*)d_ws;
    bf16_t* qb = xb + SEG;
    bf16_t* kb = qb + SEG;
    bf16_t* vb = kb + SEG;
    bf16_t* vt = xb;   // xb dead after QKV gemm
    bf16_t* ab = vb;   // vb dead after transpose

    // bf16 weights in [32MB, 40MB)
    bf16_t* wqb = vb + SEG;
    bf16_t* wkb = wqb + (size_t)DIM_ * DIM_;
    bf16_t* wvb = wkb + (size_t)DIM_ * DIM_;
    bf16_t* wob = wvb + (size_t)DIM_ * DIM_;

    cvt_all<<<dim3(4096), 256, 0, stream>>>(x, Wq, Wk, Wv, Wo, xb, wqb, wkb, wvb, wob);

    dim3 g1(DIM_ / 128, MTOT / 128, 3);
    gemm_bb<true><<<g1, 256, 0, stream>>>(
        xb, wqb, wkb, wvb, bq, bk, bv, qb, kb, vb, EXPC_, 1.f, 1.f, MTOT, DIM_, DIM_);

    dim3 gt(NN_ / 64, BB_ * HEADS_);
    transpose_v<<<gt, 256, 0, stream>>>(vb, vt);

    attn_mfma8<<<dim3(512), 512, 0, stream>>>(kb, qb, vt, ab);

    dim3 g3(DIM_ / 128, MTOT / 128, 1);
    gemm_bb<false><<<g3, 256, 0, stream>>>(
        ab, wob, wob, wob, bo, bo, bo, out, out, out, 1.f, 1.f, 1.f, MTOT, DIM_, DIM_);
}

// Round 11
// 149.199 us; speedup vs baseline: 1.2375x; 1.2375x over previous
//
#include <hip/hip_runtime.h>
#include <hip/hip_bf16.h>
#include <cstdint>
#include <cstddef>

typedef __bf16 bf16_t;
typedef __bf16 bf16x4 __attribute__((ext_vector_type(4)));
typedef __bf16 bf16x8 __attribute__((ext_vector_type(8)));
typedef float  f32x4  __attribute__((ext_vector_type(4)));
typedef float  f32x16 __attribute__((ext_vector_type(16)));
typedef unsigned int u32;
typedef unsigned int u32x4 __attribute__((ext_vector_type(4)));

#define DIM_   1024
#define HEADS_ 16
#define HD_    64
#define BB_    2
#define NN_    2048
#define MTOT   (BB_*NN_)
static constexpr float SCALE_ = 0.03125f;              // 1/sqrt(1024)
static constexpr float EXPC_  = 0.045084220027780106f; // SCALE * log2(e), folded into q-proj

// ---------------------------------------------------------------------------
// fp32 -> bf16 bulk convert, all 5 arrays in one launch.
// ---------------------------------------------------------------------------
__global__ __launch_bounds__(256) void cvt_all(
    const float* __restrict__ X,
    const float* __restrict__ W0, const float* __restrict__ W1,
    const float* __restrict__ W2, const float* __restrict__ W3,
    bf16_t* __restrict__ xo,
    bf16_t* __restrict__ o0, bf16_t* __restrict__ o1,
    bf16_t* __restrict__ o2, bf16_t* __restrict__ o3)
{
    const int bid = blockIdx.x;
    const float* src;
    bf16_t* dst;
    int lb;
    if (bid < 2048) { src = X; dst = xo; lb = bid; }
    else {
        const int w = (bid - 2048) >> 9;
        lb = (bid - 2048) & 511;
        src = (w == 0) ? W0 : (w == 1) ? W1 : (w == 2) ? W2 : W3;
        dst = (w == 0) ? o0 : (w == 1) ? o1 : (w == 2) ? o2 : o3;
    }
    const size_t i = ((size_t)lb * 256 + threadIdx.x) * 8;
    f32x4 a = *(const f32x4*)(src + i);
    f32x4 b = *(const f32x4*)(src + i + 4);
    bf16x8 o;
    o[0] = (bf16_t)a.x; o[1] = (bf16_t)a.y; o[2] = (bf16_t)a.z; o[3] = (bf16_t)a.w;
    o[4] = (bf16_t)b.x; o[5] = (bf16_t)b.y; o[6] = (bf16_t)b.z; o[7] = (bf16_t)b.w;
    *(bf16x8*)(dst + i) = o;
}

// ---------------------------------------------------------------------------
// gemm_bb8: C = (A(bf16) @ Wb(bf16)^T + bias) * osc.
// 128x128 tile, BK=64, gld16 staging, 8 waves (512 thr): wave tile 64x32.
// Same fetch/barrier structure as verified gemm_bb; 2x waves/CU.
// ---------------------------------------------------------------------------
__device__ __forceinline__ void gld16(const bf16_t* g, bf16_t* l) {
    __builtin_amdgcn_global_load_lds(
        (const __attribute__((address_space(1))) unsigned int*)g,
        (__attribute__((address_space(3))) unsigned int*)l, 16, 0, 0);
}

template<bool CBF>
__global__ __launch_bounds__(512) void gemm_bb8(
    const bf16_t* __restrict__ A,
    const bf16_t* __restrict__ W0, const bf16_t* __restrict__ W1, const bf16_t* __restrict__ W2,
    const float* __restrict__ B0, const float* __restrict__ B1, const float* __restrict__ B2,
    void* __restrict__ C0, void* __restrict__ C1, void* __restrict__ C2,
    float s0, float s1, float s2,
    int M, int N, int K)
{
    const bf16_t* Wt  = (blockIdx.z == 0) ? W0 : (blockIdx.z == 1 ? W1 : W2);
    const float* bias = (blockIdx.z == 0) ? B0 : (blockIdx.z == 1 ? B1 : B2);
    void*        Cp   = (blockIdx.z == 0) ? C0 : (blockIdx.z == 1 ? C1 : C2);
    const float  osc  = (blockIdx.z == 0) ? s0 : (blockIdx.z == 1 ? s1 : s2);

    __shared__ __align__(16) bf16_t As[128 * 64];
    __shared__ __align__(16) bf16_t Bs[128 * 64];

    const int tid  = threadIdx.x;
    const int lane = tid & 63;
    const int w    = tid >> 6;        // 0..7
    const int wr   = w >> 2;          // 0..1: 64-row half
    const int wc   = w & 3;           // 0..3: 32-col quarter
    const int bm   = blockIdx.y, bn = blockIdx.x;

    const int l15 = lane & 15;
    const int g   = lane >> 4;

    const int grow = lane >> 3;        // 0..7 within 8-row strip
    const int gcol = (lane & 7) * 8;   // bf16 col

    f32x4 acc[4][2];
    #pragma unroll
    for (int i = 0; i < 4; i++)
        #pragma unroll
        for (int j = 0; j < 2; j++)
            acc[i][j] = (f32x4){0.f, 0.f, 0.f, 0.f};

    for (int kb = 0; kb < K; kb += 64) {
        __syncthreads();
        #pragma unroll
        for (int i = 0; i < 2; i++) {
            const int r0 = i * 64 + w * 8;
            gld16(A  + (size_t)(bm * 128 + r0 + grow) * K + kb + gcol, As + r0 * 64);
            gld16(Wt + (size_t)(bn * 128 + r0 + grow) * K + kb + gcol, Bs + r0 * 64);
        }
        __syncthreads();   // drains vmcnt -> tiles ready

        #pragma unroll
        for (int kk = 0; kk < 2; kk++) {
            bf16x8 af[4], bfr[2];
            #pragma unroll
            for (int i = 0; i < 4; i++)
                af[i] = *(const bf16x8*)&As[(wr * 64 + i * 16 + l15) * 64 + kk * 32 + g * 8];
            #pragma unroll
            for (int j = 0; j < 2; j++)
                bfr[j] = *(const bf16x8*)&Bs[(wc * 32 + j * 16 + l15) * 64 + kk * 32 + g * 8];
            #pragma unroll
            for (int i = 0; i < 4; i++)
                #pragma unroll
                for (int j = 0; j < 2; j++)
                    acc[i][j] = __builtin_amdgcn_mfma_f32_16x16x32_bf16(af[i], bfr[j], acc[i][j], 0, 0, 0);
        }
    }

    const int r4 = (lane >> 4) * 4;
    #pragma unroll
    for (int j = 0; j < 2; j++) {
        const int gc = bn * 128 + wc * 32 + j * 16 + l15;
        const float bv = bias[gc];
        #pragma unroll
        for (int i = 0; i < 4; i++) {
            #pragma unroll
            for (int r = 0; r < 4; r++) {
                const int gr = bm * 128 + wr * 64 + i * 16 + r4 + r;
                const float val = (acc[i][j][r] + bv) * osc;
                if (CBF) ((bf16_t*)Cp)[(size_t)gr * N + gc] = (bf16_t)val;
                else     ((float*)Cp)[(size_t)gr * N + gc]  = val;
            }
        }
    }
}

// ---------------------------------------------------------------------------
// Per-head transpose: V[b][m][h*64+d] -> Vt[(b*16+h)*64 + d][m]
// ---------------------------------------------------------------------------
__global__ __launch_bounds__(256) void transpose_v(
    const bf16_t* __restrict__ V, bf16_t* __restrict__ Vt)
{
    __shared__ __align__(16) bf16_t Ts[64 * 72];
    const int tid = threadIdx.x;
    const int mt  = blockIdx.x;
    const int bh  = blockIdx.y;
    const int b   = bh >> 4, h = bh & 15;
    const int m0  = mt * 64;
    const int r   = tid >> 2;
    const int c   = (tid & 3) * 16;

    const bf16x8* s = (const bf16x8*)(V + ((size_t)(b * NN_ + m0 + r)) * DIM_ + h * HD_ + c);
    *(bf16x8*)(Ts + r * 72 + c)     = s[0];
    *(bf16x8*)(Ts + r * 72 + c + 8) = s[1];
    __syncthreads();

    bf16x8 o0, o1;
    #pragma unroll
    for (int i = 0; i < 8; i++) o0[i] = Ts[(c + i) * 72 + r];
    #pragma unroll
    for (int i = 0; i < 8; i++) o1[i] = Ts[(c + 8 + i) * 72 + r];
    bf16_t* dst = Vt + ((size_t)bh * HD_ + r) * NN_ + m0 + c;
    *(bf16x8*)dst       = o0;
    *(bf16x8*)(dst + 8) = o1;
}

// ---------------------------------------------------------------------------
// MFMA attention v7 (round-9 verified, 67us): 512 blocks x 512 threads.
// Waves 0-3: n-strips, m-half 0.  Waves 4-7: same n, m-half 1.
// Double-buffered K/V KVBLK=128, 1 barrier/tile, LDS merge at end.
// ---------------------------------------------------------------------------
__device__ __forceinline__ u32 cvtpk_bf16(float lo, float hi) {
    u32 d;
    asm volatile("v_cvt_pk_bf16_f32 %0, %1, %2" : "=v"(d) : "v"(lo), "v"(hi));
    return d;
}

__global__ __launch_bounds__(512, 4) void attn_mfma7(
    const bf16_t* __restrict__ Qa,   // kb (attention-query rows n)
    const bf16_t* __restrict__ Ka,   // qb (attention-key rows m, pre-scaled by EXPC_)
    const bf16_t* __restrict__ Vtg,  // V^T per head [bh][d][m]
    bf16_t* __restrict__ O)
{
    __shared__ __align__(16) bf16_t Kt[2][128 * 72];   // 36.9 KB
    __shared__ __align__(16) bf16_t Vt[2][64 * 136];   // 34.8 KB

    const int tid  = threadIdx.x;
    const int lane = tid & 63;
    const int w    = tid >> 6;       // 0..7
    const int l31  = lane & 31;
    const int h5   = lane >> 5;

    const int nw = (w & 3) * 32;     // wave's n-offset in block
    const int mo = (w >> 2) * 64;    // wave's m-half within each 128-m tile

    // XCD-chunked swizzle: 512 blocks, 64 consecutive ids per XCD
    const int wg = blockIdx.x;
    const int id = (wg & 7) * 64 + (wg >> 3);
    const int bh = id >> 4;          // 0..31
    const int nt = id & 15;          // 0..15
    const int b  = bh >> 4, h = bh & 15;
    const int n0 = nt * 128;

    const size_t base = (size_t)b * NN_ * DIM_ + h * HD_;

    // Q-fragments (B-operand, n = n0 + nw + l31) straight from global
    const bf16_t* qrow = Qa + base + (size_t)(n0 + nw + l31) * DIM_ + h5 * 8;
    bf16x8 qf[4];
    #pragma unroll
    for (int ks = 0; ks < 4; ks++)
        qf[ks] = *(const bf16x8*)(qrow + ks * 16);

    u32x4 onesw;
    onesw.x = 0x3F803F80u; onesw.y = 0x3F803F80u; onesw.z = 0x3F803F80u; onesw.w = 0x3F803F80u;
    const bf16x8 onesf = __builtin_bit_cast(bf16x8, onesw);

    f32x16 oa0 = {}, oa1 = {}, oL = {};

    const bf16_t* vrow   = Vtg + (size_t)bh * HD_ * NN_;
    const bf16_t* kgbase = Ka + base;

    // staging (512 threads): K 128x64 (2 rows/thread of 8), V^T 64x128 (16 m)
    const int kr2 = tid >> 3;          // 0..63
    const int kc2 = (tid & 7) * 8;     // K d-col: 0..56
    const int vc2 = (tid & 7) * 16;    // V m-col: 0..112

    bf16x8 kA0, kB0, vA0, vA1;

    #define ISSUE(m0)                                                                        \
        {                                                                                    \
            kA0 = *(const bf16x8*)(kgbase + (size_t)((m0) + kr2) * DIM_ + kc2);              \
            kB0 = *(const bf16x8*)(kgbase + (size_t)((m0) + 64 + kr2) * DIM_ + kc2);         \
            const bf16x8* vp = (const bf16x8*)(vrow + (size_t)kr2 * NN_ + (m0) + vc2);       \
            vA0 = vp[0]; vA1 = vp[1];                                                        \
        }
    #define COMMIT(buf)                                                                      \
        {                                                                                    \
            *(bf16x8*)(Kt[buf] + kr2 * 72 + kc2)        = kA0;                               \
            *(bf16x8*)(Kt[buf] + (64 + kr2) * 72 + kc2) = kB0;                               \
            bf16_t* vd = Vt[buf] + kr2 * 136 + vc2;                                          \
            *(bf16x8*)(vd)     = vA0;                                                        \
            *(bf16x8*)(vd + 8) = vA1;                                                        \
        }

    ISSUE(0);
    COMMIT(0);
    __syncthreads();

    for (int mt = 0; mt < NN_ / 128; mt++) {
        const int cur = mt & 1;
        if (mt < NN_ / 128 - 1) ISSUE((mt + 1) * 128);

        const bf16_t* KtC = Kt[cur];
        const bf16_t* VtC = Vt[cur];

        // S^T for this wave's m-half: lane holds 32 P-vals for n = nw + l31
        f32x16 sa0 = {}, sa1 = {};
        __builtin_amdgcn_s_setprio(1);
        #pragma unroll
        for (int ks = 0; ks < 4; ks++) {
            bf16x8 kf0 = *(const bf16x8*)&KtC[(mo + l31) * 72 + ks * 16 + h5 * 8];
            bf16x8 kf1 = *(const bf16x8*)&KtC[(mo + 32 + l31) * 72 + ks * 16 + h5 * 8];
            sa0 = __builtin_amdgcn_mfma_f32_32x32x16_bf16(kf0, qf[ks], sa0, 0, 0, 0);
            sa1 = __builtin_amdgcn_mfma_f32_32x32x16_bf16(kf1, qf[ks], sa1, 0, 0, 0);
        }
        __builtin_amdgcn_s_setprio(0);

        // P = exp2(S^T)  (scale pre-folded into Ka)
        float p0[16], p1[16];
        #pragma unroll
        for (int r = 0; r < 16; r++) { p0[r] = exp2f(sa0[r]); p1[r] = exp2f(sa1[r]); }

        // PV A-fragments in-register: 16 cvt_pk + 8 permlane32_swap
        bf16x8 pf[4];
        #pragma unroll
        for (int mb = 0; mb < 4; mb++) {
            const float* pp = (mb & 2) ? p1 : p0;
            const int rb = (mb & 1) * 8;
            u32 x0 = cvtpk_bf16(pp[rb + 0], pp[rb + 1]);
            u32 x1 = cvtpk_bf16(pp[rb + 2], pp[rb + 3]);
            u32 y0 = cvtpk_bf16(pp[rb + 4], pp[rb + 5]);
            u32 y1 = cvtpk_bf16(pp[rb + 6], pp[rb + 7]);
            asm volatile("v_permlane32_swap_b32 %0, %1" : "+v"(x0), "+v"(y0));
            asm volatile("v_permlane32_swap_b32 %0, %1" : "+v"(x1), "+v"(y1));
            u32x4 t; t.x = x0; t.y = x1; t.z = y0; t.w = y1;
            pf[mb] = __builtin_bit_cast(bf16x8, t);
        }

        // O += P·V ; L += P·1   (this wave's m-half)
        __builtin_amdgcn_s_setprio(1);
        #pragma unroll
        for (int ms = 0; ms < 4; ms++) {
            bf16x8 vf0 = *(const bf16x8*)&VtC[l31 * 136 + mo + ms * 16 + h5 * 8];
            bf16x8 vf1 = *(const bf16x8*)&VtC[(32 + l31) * 136 + mo + ms * 16 + h5 * 8];
            oa0 = __builtin_amdgcn_mfma_f32_32x32x16_bf16(pf[ms], vf0, oa0, 0, 0, 0);
            oa1 = __builtin_amdgcn_mfma_f32_32x32x16_bf16(pf[ms], vf1, oa1, 0, 0, 0);
            oL  = __builtin_amdgcn_mfma_f32_32x32x16_bf16(pf[ms], onesf, oL, 0, 0, 0);
        }
        __builtin_amdgcn_s_setprio(0);

        if (mt < NN_ / 128 - 1) COMMIT(cur ^ 1);
        __syncthreads();
    }
    #undef ISSUE
    #undef COMMIT

    // merge m-half partials: waves 4-7 write 48 f32/lane, waves 0-3 add.
    if (w >= 4) {
        float* buf = (w < 6) ? ((float*)Kt + (w - 4) * 3072)
                             : ((float*)Vt + (w - 6) * 3072);
        #pragma unroll
        for (int reg = 0; reg < 16; reg++) {
            buf[reg * 64 + lane]        = oa0[reg];
            buf[1024 + reg * 64 + lane] = oa1[reg];
            buf[2048 + reg * 64 + lane] = oL[reg];
        }
    }
    __syncthreads();
    if (w < 4) {
        const float* buf = (w < 2) ? ((const float*)Kt + w * 3072)
                                   : ((const float*)Vt + (w - 2) * 3072);
        #pragma unroll
        for (int reg = 0; reg < 16; reg++) {
            oa0[reg] += buf[reg * 64 + lane];
            oa1[reg] += buf[1024 + reg * 64 + lane];
            oL[reg]  += buf[2048 + reg * 64 + lane];
        }
        // epilogue: row n = (reg&3)+8*(reg>>2)+4*h5; oL has identical mapping
        #pragma unroll
        for (int reg = 0; reg < 16; reg++) {
            const int nr = (reg & 3) + 8 * (reg >> 2) + 4 * h5;
            const float il = 1.f / oL[reg];
            const size_t rowoff = base + (size_t)(n0 + nw + nr) * DIM_;
            O[rowoff + l31]      = (bf16_t)(oa0[reg] * il);
            O[rowoff + 32 + l31] = (bf16_t)(oa1[reg] * il);
        }
    }
}

// ---------------------------------------------------------------------------
extern "C" void kernel_launch(void* const* d_in, const int* in_sizes, int n_in,
                              void* d_out, int out_size, void* d_ws, size_t ws_size,
                              hipStream_t stream)
{
    const float* x  = (const float*)d_in[0];
    const float* Wq = (const float*)d_in[1];
    const float* bq = (const float*)d_in[2];
    const float* Wk = (const float*)d_in[3];
    const float* bk = (const float*)d_in[4];
    const float* Wv = (const float*)d_in[5];
    const float* bv = (const float*)d_in[6];
    const float* Wo = (const float*)d_in[7];
    const float* bo = (const float*)d_in[8];
    float* out = (float*)d_out;

    const size_t SEG = (size_t)MTOT * DIM_;   // 4M elems = 8MB bf16
    bf16_t* xb = (bf16_t*)d_ws;
    bf16_t* qb = xb + SEG;
    bf16_t* kb = qb + SEG;
    bf16_t* vb = kb + SEG;
    bf16_t* vt = xb;   // xb dead after QKV gemm
    bf16_t* ab = vb;   // vb dead after transpose

    // bf16 weights in [32MB, 40MB)
    bf16_t* wqb = vb + SEG;
    bf16_t* wkb = wqb + (size_t)DIM_ * DIM_;
    bf16_t* wvb = wkb + (size_t)DIM_ * DIM_;
    bf16_t* wob = wvb + (size_t)DIM_ * DIM_;

    cvt_all<<<dim3(4096), 256, 0, stream>>>(x, Wq, Wk, Wv, Wo, xb, wqb, wkb, wvb, wob);

    dim3 g1(DIM_ / 128, MTOT / 128, 3);
    gemm_bb8<true><<<g1, 512, 0, stream>>>(
        xb, wqb, wkb, wvb, bq, bk, bv, qb, kb, vb, EXPC_, 1.f, 1.f, MTOT, DIM_, DIM_);

    dim3 gt(NN_ / 64, BB_ * HEADS_);
    transpose_v<<<gt, 256, 0, stream>>>(vb, vt);

    attn_mfma7<<<dim3(512), 512, 0, stream>>>(kb, qb, vt, ab);

    dim3 g3(DIM_ / 128, MTOT / 128, 1);
    gemm_bb8<false><<<g3, 512, 0, stream>>>(
        ab, wob, wob, wob, bo, bo, bo, out, out, out, 1.f, 1.f, 1.f, MTOT, DIM_, DIM_);
}

// Round 12
// 125.256 us; speedup vs baseline: 1.4740x; 1.1912x over previous
//
#include <hip/hip_runtime.h>
#include <hip/hip_bf16.h>
#include <cstdint>
#include <cstddef>

typedef __bf16 bf16_t;
typedef __bf16 bf16x4 __attribute__((ext_vector_type(4)));
typedef __bf16 bf16x8 __attribute__((ext_vector_type(8)));
typedef float  f32x4  __attribute__((ext_vector_type(4)));
typedef float  f32x16 __attribute__((ext_vector_type(16)));
typedef unsigned int u32;
typedef unsigned int u32x4 __attribute__((ext_vector_type(4)));

#define DIM_   1024
#define HEADS_ 16
#define HD_    64
#define BB_    2
#define NN_    2048
#define MTOT   (BB_*NN_)
static constexpr float SCALE_ = 0.03125f;              // 1/sqrt(1024)
static constexpr float EXPC_  = 0.045084220027780106f; // SCALE * log2(e), folded into q-proj

__device__ __forceinline__ float exp2_hw(float x) {
    float r;
    asm("v_exp_f32 %0, %1" : "=v"(r) : "v"(x));
    return r;
}

// ---------------------------------------------------------------------------
// fp32 -> bf16 bulk convert, all 5 arrays in one launch.
// ---------------------------------------------------------------------------
__global__ __launch_bounds__(256) void cvt_all(
    const float* __restrict__ X,
    const float* __restrict__ W0, const float* __restrict__ W1,
    const float* __restrict__ W2, const float* __restrict__ W3,
    bf16_t* __restrict__ xo,
    bf16_t* __restrict__ o0, bf16_t* __restrict__ o1,
    bf16_t* __restrict__ o2, bf16_t* __restrict__ o3)
{
    const int bid = blockIdx.x;
    const float* src;
    bf16_t* dst;
    int lb;
    if (bid < 2048) { src = X; dst = xo; lb = bid; }
    else {
        const int w = (bid - 2048) >> 9;
        lb = (bid - 2048) & 511;
        src = (w == 0) ? W0 : (w == 1) ? W1 : (w == 2) ? W2 : W3;
        dst = (w == 0) ? o0 : (w == 1) ? o1 : (w == 2) ? o2 : o3;
    }
    const size_t i = ((size_t)lb * 256 + threadIdx.x) * 8;
    f32x4 a = *(const f32x4*)(src + i);
    f32x4 b = *(const f32x4*)(src + i + 4);
    bf16x8 o;
    o[0] = (bf16_t)a.x; o[1] = (bf16_t)a.y; o[2] = (bf16_t)a.z; o[3] = (bf16_t)a.w;
    o[4] = (bf16_t)b.x; o[5] = (bf16_t)b.y; o[6] = (bf16_t)b.z; o[7] = (bf16_t)b.w;
    *(bf16x8*)(dst + i) = o;
}

// ---------------------------------------------------------------------------
__device__ __forceinline__ void gld16(const bf16_t* g, bf16_t* l) {
    __builtin_amdgcn_global_load_lds(
        (const __attribute__((address_space(1))) unsigned int*)g,
        (__attribute__((address_space(3))) unsigned int*)l, 16, 0, 0);
}

// ---------------------------------------------------------------------------
// Fused QKV GEMM: per block, A tile [128 x k] x {Wq,Wk,Wv} tiles [64 x k].
// grid (N/64=16, M/128=32) = 512 blocks, 512 threads (8 waves).
// Wave tile 32x32 per output (4 row-strips x 2 col-strips). q out scaled EXPC_.
// ---------------------------------------------------------------------------
__global__ __launch_bounds__(512) void gemm_qkv(
    const bf16_t* __restrict__ A,
    const bf16_t* __restrict__ Wq, const bf16_t* __restrict__ Wk, const bf16_t* __restrict__ Wv,
    const float* __restrict__ bq, const float* __restrict__ bk, const float* __restrict__ bv,
    bf16_t* __restrict__ Cq, bf16_t* __restrict__ Ck, bf16_t* __restrict__ Cv)
{
    __shared__ __align__(16) bf16_t As[128 * 64];     // 16KB
    __shared__ __align__(16) bf16_t Bs[3][64 * 64];   // 24KB

    const int tid  = threadIdx.x;
    const int lane = tid & 63;
    const int w    = tid >> 6;        // 0..7
    const int wr   = w >> 1;          // 0..3: 32-row strip
    const int wc   = w & 1;           // 0..1: 32-col half
    const int bn   = blockIdx.x;      // 0..15 (64-col tile)
    const int bm   = blockIdx.y;      // 0..31 (128-row tile)

    const int l15 = lane & 15;
    const int g   = lane >> 4;

    const int srow = lane >> 3;        // 0..7 within 8-row chunk
    const int scol = (lane & 7) * 8;   // bf16 col

    f32x4 aq[2][2], ak[2][2], av[2][2];
    #pragma unroll
    for (int i = 0; i < 2; i++)
        #pragma unroll
        for (int j = 0; j < 2; j++) {
            aq[i][j] = (f32x4){0.f, 0.f, 0.f, 0.f};
            ak[i][j] = (f32x4){0.f, 0.f, 0.f, 0.f};
            av[i][j] = (f32x4){0.f, 0.f, 0.f, 0.f};
        }

    for (int kb = 0; kb < DIM_; kb += 64) {
        __syncthreads();
        // A: 16 chunks of 8 rows; wave w stages chunks 2w, 2w+1
        #pragma unroll
        for (int c2 = 0; c2 < 2; c2++) {
            const int chunk = w * 2 + c2;
            gld16(A + (size_t)(bm * 128 + chunk * 8 + srow) * DIM_ + kb + scol,
                  As + chunk * 512);
        }
        // each W: 8 chunks; wave w stages chunk w of each
        gld16(Wq + (size_t)(bn * 64 + w * 8 + srow) * DIM_ + kb + scol, &Bs[0][0] + w * 512);
        gld16(Wk + (size_t)(bn * 64 + w * 8 + srow) * DIM_ + kb + scol, &Bs[1][0] + w * 512);
        gld16(Wv + (size_t)(bn * 64 + w * 8 + srow) * DIM_ + kb + scol, &Bs[2][0] + w * 512);
        __syncthreads();

        #pragma unroll
        for (int kk = 0; kk < 2; kk++) {
            bf16x8 af[2];
            #pragma unroll
            for (int i = 0; i < 2; i++)
                af[i] = *(const bf16x8*)&As[(wr * 32 + i * 16 + l15) * 64 + kk * 32 + g * 8];
            bf16x8 bqf[2], bkf[2], bvf[2];
            #pragma unroll
            for (int j = 0; j < 2; j++) {
                const int off = (wc * 32 + j * 16 + l15) * 64 + kk * 32 + g * 8;
                bqf[j] = *(const bf16x8*)&Bs[0][off];
                bkf[j] = *(const bf16x8*)&Bs[1][off];
                bvf[j] = *(const bf16x8*)&Bs[2][off];
            }
            #pragma unroll
            for (int i = 0; i < 2; i++)
                #pragma unroll
                for (int j = 0; j < 2; j++) {
                    aq[i][j] = __builtin_amdgcn_mfma_f32_16x16x32_bf16(af[i], bqf[j], aq[i][j], 0, 0, 0);
                    ak[i][j] = __builtin_amdgcn_mfma_f32_16x16x32_bf16(af[i], bkf[j], ak[i][j], 0, 0, 0);
                    av[i][j] = __builtin_amdgcn_mfma_f32_16x16x32_bf16(af[i], bvf[j], av[i][j], 0, 0, 0);
                }
        }
    }

    const int r4 = g * 4;
    #pragma unroll
    for (int j = 0; j < 2; j++) {
        const int gc = bn * 64 + wc * 32 + j * 16 + l15;
        const float vq = bq[gc], vk = bk[gc], vv = bv[gc];
        #pragma unroll
        for (int i = 0; i < 2; i++) {
            #pragma unroll
            for (int r = 0; r < 4; r++) {
                const size_t gr = (size_t)(bm * 128 + wr * 32 + i * 16 + r4 + r) * DIM_ + gc;
                Cq[gr] = (bf16_t)((aq[i][j][r] + vq) * EXPC_);
                Ck[gr] = (bf16_t)(ak[i][j][r] + vk);
                Cv[gr] = (bf16_t)(av[i][j][r] + vv);
            }
        }
    }
}

// ---------------------------------------------------------------------------
// O-proj GEMM: C(f32) = A(bf16) @ Wo^T + bo.  BM=64, BN=128,
// grid (8, 64) = 512 blocks, 512 threads; wave tile 32x32 (2r x 4c).
// ---------------------------------------------------------------------------
__global__ __launch_bounds__(512) void gemm_o(
    const bf16_t* __restrict__ A, const bf16_t* __restrict__ Wo,
    const float* __restrict__ bo, float* __restrict__ C)
{
    __shared__ __align__(16) bf16_t As[64 * 64];      // 8KB
    __shared__ __align__(16) bf16_t Bs[128 * 64];     // 16KB

    const int tid  = threadIdx.x;
    const int lane = tid & 63;
    const int w    = tid >> 6;        // 0..7
    const int wr   = w & 1;           // 0..1: 32-row strip
    const int wc   = w >> 1;          // 0..3: 32-col strip
    const int bn   = blockIdx.x;      // 0..7
    const int bm   = blockIdx.y;      // 0..63

    const int l15 = lane & 15;
    const int g   = lane >> 4;

    const int srow = lane >> 3;
    const int scol = (lane & 7) * 8;

    f32x4 acc[2][2];
    #pragma unroll
    for (int i = 0; i < 2; i++)
        #pragma unroll
        for (int j = 0; j < 2; j++)
            acc[i][j] = (f32x4){0.f, 0.f, 0.f, 0.f};

    for (int kb = 0; kb < DIM_; kb += 64) {
        __syncthreads();
        // A: 8 chunks; wave w stages chunk w
        gld16(A + (size_t)(bm * 64 + w * 8 + srow) * DIM_ + kb + scol, As + w * 512);
        // B: 16 chunks; wave w stages 2w, 2w+1
        #pragma unroll
        for (int c2 = 0; c2 < 2; c2++) {
            const int chunk = w * 2 + c2;
            gld16(Wo + (size_t)(bn * 128 + chunk * 8 + srow) * DIM_ + kb + scol,
                  Bs + chunk * 512);
        }
        __syncthreads();

        #pragma unroll
        for (int kk = 0; kk < 2; kk++) {
            bf16x8 af[2], bf[2];
            #pragma unroll
            for (int i = 0; i < 2; i++)
                af[i] = *(const bf16x8*)&As[(wr * 32 + i * 16 + l15) * 64 + kk * 32 + g * 8];
            #pragma unroll
            for (int j = 0; j < 2; j++)
                bf[j] = *(const bf16x8*)&Bs[(wc * 32 + j * 16 + l15) * 64 + kk * 32 + g * 8];
            #pragma unroll
            for (int i = 0; i < 2; i++)
                #pragma unroll
                for (int j = 0; j < 2; j++)
                    acc[i][j] = __builtin_amdgcn_mfma_f32_16x16x32_bf16(af[i], bf[j], acc[i][j], 0, 0, 0);
        }
    }

    const int r4 = g * 4;
    #pragma unroll
    for (int j = 0; j < 2; j++) {
        const int gc = bn * 128 + wc * 32 + j * 16 + l15;
        const float bv = bo[gc];
        #pragma unroll
        for (int i = 0; i < 2; i++) {
            #pragma unroll
            for (int r = 0; r < 4; r++) {
                const size_t gr = (size_t)(bm * 64 + wr * 32 + i * 16 + r4 + r) * DIM_ + gc;
                C[gr] = acc[i][j][r] + bv;
            }
        }
    }
}

// ---------------------------------------------------------------------------
// Per-head transpose: V[b][m][h*64+d] -> Vt[(b*16+h)*64 + d][m]
// ---------------------------------------------------------------------------
__global__ __launch_bounds__(256) void transpose_v(
    const bf16_t* __restrict__ V, bf16_t* __restrict__ Vt)
{
    __shared__ __align__(16) bf16_t Ts[64 * 72];
    const int tid = threadIdx.x;
    const int mt  = blockIdx.x;
    const int bh  = blockIdx.y;
    const int b   = bh >> 4, h = bh & 15;
    const int m0  = mt * 64;
    const int r   = tid >> 2;
    const int c   = (tid & 3) * 16;

    const bf16x8* s = (const bf16x8*)(V + ((size_t)(b * NN_ + m0 + r)) * DIM_ + h * HD_ + c);
    *(bf16x8*)(Ts + r * 72 + c)     = s[0];
    *(bf16x8*)(Ts + r * 72 + c + 8) = s[1];
    __syncthreads();

    bf16x8 o0, o1;
    #pragma unroll
    for (int i = 0; i < 8; i++) o0[i] = Ts[(c + i) * 72 + r];
    #pragma unroll
    for (int i = 0; i < 8; i++) o1[i] = Ts[(c + 8 + i) * 72 + r];
    bf16_t* dst = Vt + ((size_t)bh * HD_ + r) * NN_ + m0 + c;
    *(bf16x8*)dst       = o0;
    *(bf16x8*)(dst + 8) = o1;
}

// ---------------------------------------------------------------------------
// MFMA attention v7 (verified structure, round 9/11) + hw exp2.
// ---------------------------------------------------------------------------
__device__ __forceinline__ u32 cvtpk_bf16(float lo, float hi) {
    u32 d;
    asm volatile("v_cvt_pk_bf16_f32 %0, %1, %2" : "=v"(d) : "v"(lo), "v"(hi));
    return d;
}

__global__ __launch_bounds__(512, 4) void attn_mfma7(
    const bf16_t* __restrict__ Qa,   // kb (attention-query rows n)
    const bf16_t* __restrict__ Ka,   // qb (attention-key rows m, pre-scaled by EXPC_)
    const bf16_t* __restrict__ Vtg,  // V^T per head [bh][d][m]
    bf16_t* __restrict__ O)
{
    __shared__ __align__(16) bf16_t Kt[2][128 * 72];   // 36.9 KB
    __shared__ __align__(16) bf16_t Vt[2][64 * 136];   // 34.8 KB

    const int tid  = threadIdx.x;
    const int lane = tid & 63;
    const int w    = tid >> 6;       // 0..7
    const int l31  = lane & 31;
    const int h5   = lane >> 5;

    const int nw = (w & 3) * 32;     // wave's n-offset in block
    const int mo = (w >> 2) * 64;    // wave's m-half within each 128-m tile

    const int wg = blockIdx.x;
    const int id = (wg & 7) * 64 + (wg >> 3);
    const int bh = id >> 4;          // 0..31
    const int nt = id & 15;          // 0..15
    const int b  = bh >> 4, h = bh & 15;
    const int n0 = nt * 128;

    const size_t base = (size_t)b * NN_ * DIM_ + h * HD_;

    const bf16_t* qrow = Qa + base + (size_t)(n0 + nw + l31) * DIM_ + h5 * 8;
    bf16x8 qf[4];
    #pragma unroll
    for (int ks = 0; ks < 4; ks++)
        qf[ks] = *(const bf16x8*)(qrow + ks * 16);

    u32x4 onesw;
    onesw.x = 0x3F803F80u; onesw.y = 0x3F803F80u; onesw.z = 0x3F803F80u; onesw.w = 0x3F803F80u;
    const bf16x8 onesf = __builtin_bit_cast(bf16x8, onesw);

    f32x16 oa0 = {}, oa1 = {}, oL = {};

    const bf16_t* vrow   = Vtg + (size_t)bh * HD_ * NN_;
    const bf16_t* kgbase = Ka + base;

    const int kr2 = tid >> 3;          // 0..63
    const int kc2 = (tid & 7) * 8;     // K d-col: 0..56
    const int vc2 = (tid & 7) * 16;    // V m-col: 0..112

    bf16x8 kA0, kB0, vA0, vA1;

    #define ISSUE(m0)                                                                        \
        {                                                                                    \
            kA0 = *(const bf16x8*)(kgbase + (size_t)((m0) + kr2) * DIM_ + kc2);              \
            kB0 = *(const bf16x8*)(kgbase + (size_t)((m0) + 64 + kr2) * DIM_ + kc2);         \
            const bf16x8* vp = (const bf16x8*)(vrow + (size_t)kr2 * NN_ + (m0) + vc2);       \
            vA0 = vp[0]; vA1 = vp[1];                                                        \
        }
    #define COMMIT(buf)                                                                      \
        {                                                                                    \
            *(bf16x8*)(Kt[buf] + kr2 * 72 + kc2)        = kA0;                               \
            *(bf16x8*)(Kt[buf] + (64 + kr2) * 72 + kc2) = kB0;                               \
            bf16_t* vd = Vt[buf] + kr2 * 136 + vc2;                                          \
            *(bf16x8*)(vd)     = vA0;                                                        \
            *(bf16x8*)(vd + 8) = vA1;                                                        \
        }

    ISSUE(0);
    COMMIT(0);
    __syncthreads();

    for (int mt = 0; mt < NN_ / 128; mt++) {
        const int cur = mt & 1;
        if (mt < NN_ / 128 - 1) ISSUE((mt + 1) * 128);

        const bf16_t* KtC = Kt[cur];
        const bf16_t* VtC = Vt[cur];

        f32x16 sa0 = {}, sa1 = {};
        __builtin_amdgcn_s_setprio(1);
        #pragma unroll
        for (int ks = 0; ks < 4; ks++) {
            bf16x8 kf0 = *(const bf16x8*)&KtC[(mo + l31) * 72 + ks * 16 + h5 * 8];
            bf16x8 kf1 = *(const bf16x8*)&KtC[(mo + 32 + l31) * 72 + ks * 16 + h5 * 8];
            sa0 = __builtin_amdgcn_mfma_f32_32x32x16_bf16(kf0, qf[ks], sa0, 0, 0, 0);
            sa1 = __builtin_amdgcn_mfma_f32_32x32x16_bf16(kf1, qf[ks], sa1, 0, 0, 0);
        }
        __builtin_amdgcn_s_setprio(0);

        // P = exp2(S^T) via hw v_exp_f32 (scale pre-folded into Ka)
        float p0[16], p1[16];
        #pragma unroll
        for (int r = 0; r < 16; r++) { p0[r] = exp2_hw(sa0[r]); p1[r] = exp2_hw(sa1[r]); }

        bf16x8 pf[4];
        #pragma unroll
        for (int mb = 0; mb < 4; mb++) {
            const float* pp = (mb & 2) ? p1 : p0;
            const int rb = (mb & 1) * 8;
            u32 x0 = cvtpk_bf16(pp[rb + 0], pp[rb + 1]);
            u32 x1 = cvtpk_bf16(pp[rb + 2], pp[rb + 3]);
            u32 y0 = cvtpk_bf16(pp[rb + 4], pp[rb + 5]);
            u32 y1 = cvtpk_bf16(pp[rb + 6], pp[rb + 7]);
            asm volatile("v_permlane32_swap_b32 %0, %1" : "+v"(x0), "+v"(y0));
            asm volatile("v_permlane32_swap_b32 %0, %1" : "+v"(x1), "+v"(y1));
            u32x4 t; t.x = x0; t.y = x1; t.z = y0; t.w = y1;
            pf[mb] = __builtin_bit_cast(bf16x8, t);
        }

        __builtin_amdgcn_s_setprio(1);
        #pragma unroll
        for (int ms = 0; ms < 4; ms++) {
            bf16x8 vf0 = *(const bf16x8*)&VtC[l31 * 136 + mo + ms * 16 + h5 * 8];
            bf16x8 vf1 = *(const bf16x8*)&VtC[(32 + l31) * 136 + mo + ms * 16 + h5 * 8];
            oa0 = __builtin_amdgcn_mfma_f32_32x32x16_bf16(pf[ms], vf0, oa0, 0, 0, 0);
            oa1 = __builtin_amdgcn_mfma_f32_32x32x16_bf16(pf[ms], vf1, oa1, 0, 0, 0);
            oL  = __builtin_amdgcn_mfma_f32_32x32x16_bf16(pf[ms], onesf, oL, 0, 0, 0);
        }
        __builtin_amdgcn_s_setprio(0);

        if (mt < NN_ / 128 - 1) COMMIT(cur ^ 1);
        __syncthreads();
    }
    #undef ISSUE
    #undef COMMIT

    if (w >= 4) {
        float* buf = (w < 6) ? ((float*)Kt + (w - 4) * 3072)
                             : ((float*)Vt + (w - 6) * 3072);
        #pragma unroll
        for (int reg = 0; reg < 16; reg++) {
            buf[reg * 64 + lane]        = oa0[reg];
            buf[1024 + reg * 64 + lane] = oa1[reg];
            buf[2048 + reg * 64 + lane] = oL[reg];
        }
    }
    __syncthreads();
    if (w < 4) {
        const float* buf = (w < 2) ? ((const float*)Kt + w * 3072)
                                   : ((const float*)Vt + (w - 2) * 3072);
        #pragma unroll
        for (int reg = 0; reg < 16; reg++) {
            oa0[reg] += buf[reg * 64 + lane];
            oa1[reg] += buf[1024 + reg * 64 + lane];
            oL[reg]  += buf[2048 + reg * 64 + lane];
        }
        #pragma unroll
        for (int reg = 0; reg < 16; reg++) {
            const int nr = (reg & 3) + 8 * (reg >> 2) + 4 * h5;
            const float il = 1.f / oL[reg];
            const size_t rowoff = base + (size_t)(n0 + nw + nr) * DIM_;
            O[rowoff + l31]      = (bf16_t)(oa0[reg] * il);
            O[rowoff + 32 + l31] = (bf16_t)(oa1[reg] * il);
        }
    }
}

// ---------------------------------------------------------------------------
extern "C" void kernel_launch(void* const* d_in, const int* in_sizes, int n_in,
                              void* d_out, int out_size, void* d_ws, size_t ws_size,
                              hipStream_t stream)
{
    const float* x  = (const float*)d_in[0];
    const float* Wq = (const float*)d_in[1];
    const float* bq = (const float*)d_in[2];
    const float* Wk = (const float*)d_in[3];
    const float* bk = (const float*)d_in[4];
    const float* Wv = (const float*)d_in[5];
    const float* bv = (const float*)d_in[6];
    const float* Wo = (const float*)d_in[7];
    const float* bo = (const float*)d_in[8];
    float* out = (float*)d_out;

    const size_t SEG = (size_t)MTOT * DIM_;   // 4M elems = 8MB bf16
    bf16_t* xb = (bf16_t*)d_ws;
    bf16_t* qb = xb + SEG;
    bf16_t* kb = qb + SEG;
    bf16_t* vb = kb + SEG;
    bf16_t* vt = xb;   // xb dead after QKV gemm
    bf16_t* ab = vb;   // vb dead after transpose

    // bf16 weights in [32MB, 40MB)
    bf16_t* wqb = vb + SEG;
    bf16_t* wkb = wqb + (size_t)DIM_ * DIM_;
    bf16_t* wvb = wkb + (size_t)DIM_ * DIM_;
    bf16_t* wob = wvb + (size_t)DIM_ * DIM_;

    cvt_all<<<dim3(4096), 256, 0, stream>>>(x, Wq, Wk, Wv, Wo, xb, wqb, wkb, wvb, wob);

    gemm_qkv<<<dim3(16, 32), 512, 0, stream>>>(
        xb, wqb, wkb, wvb, bq, bk, bv, qb, kb, vb);

    dim3 gt(NN_ / 64, BB_ * HEADS_);
    transpose_v<<<gt, 256, 0, stream>>>(vb, vt);

    attn_mfma7<<<dim3(512), 512, 0, stream>>>(kb, qb, vt, ab);

    gemm_o<<<dim3(8, 64), 512, 0, stream>>>(ab, wob, bo, out);
}

// Round 13
// 118.118 us; speedup vs baseline: 1.5631x; 1.0604x over previous
//
#include <hip/hip_runtime.h>
#include <hip/hip_bf16.h>
#include <cstdint>
#include <cstddef>

typedef __bf16 bf16_t;
typedef __bf16 bf16x4 __attribute__((ext_vector_type(4)));
typedef __bf16 bf16x8 __attribute__((ext_vector_type(8)));
typedef float  f32x4  __attribute__((ext_vector_type(4)));
typedef float  f32x16 __attribute__((ext_vector_type(16)));
typedef unsigned int u32;
typedef unsigned int u32x4 __attribute__((ext_vector_type(4)));

#define DIM_   1024
#define HEADS_ 16
#define HD_    64
#define BB_    2
#define NN_    2048
#define MTOT   (BB_*NN_)
static constexpr float SCALE_ = 0.03125f;              // 1/sqrt(1024)
static constexpr float EXPC_  = 0.045084220027780106f; // SCALE * log2(e), folded into q-proj

__device__ __forceinline__ float exp2_hw(float x) {
    float r;
    asm("v_exp_f32 %0, %1" : "=v"(r) : "v"(x));
    return r;
}

// ---------------------------------------------------------------------------
// fp32 -> bf16 bulk convert, all 5 arrays in one launch.
// ---------------------------------------------------------------------------
__global__ __launch_bounds__(256) void cvt_all(
    const float* __restrict__ X,
    const float* __restrict__ W0, const float* __restrict__ W1,
    const float* __restrict__ W2, const float* __restrict__ W3,
    bf16_t* __restrict__ xo,
    bf16_t* __restrict__ o0, bf16_t* __restrict__ o1,
    bf16_t* __restrict__ o2, bf16_t* __restrict__ o3)
{
    const int bid = blockIdx.x;
    const float* src;
    bf16_t* dst;
    int lb;
    if (bid < 2048) { src = X; dst = xo; lb = bid; }
    else {
        const int w = (bid - 2048) >> 9;
        lb = (bid - 2048) & 511;
        src = (w == 0) ? W0 : (w == 1) ? W1 : (w == 2) ? W2 : W3;
        dst = (w == 0) ? o0 : (w == 1) ? o1 : (w == 2) ? o2 : o3;
    }
    const size_t i = ((size_t)lb * 256 + threadIdx.x) * 8;
    f32x4 a = *(const f32x4*)(src + i);
    f32x4 b = *(const f32x4*)(src + i + 4);
    bf16x8 o;
    o[0] = (bf16_t)a.x; o[1] = (bf16_t)a.y; o[2] = (bf16_t)a.z; o[3] = (bf16_t)a.w;
    o[4] = (bf16_t)b.x; o[5] = (bf16_t)b.y; o[6] = (bf16_t)b.z; o[7] = (bf16_t)b.w;
    *(bf16x8*)(dst + i) = o;
}

// ---------------------------------------------------------------------------
__device__ __forceinline__ void gld16(const bf16_t* g, bf16_t* l) {
    __builtin_amdgcn_global_load_lds(
        (const __attribute__((address_space(1))) unsigned int*)g,
        (__attribute__((address_space(3))) unsigned int*)l, 16, 0, 0);
}

// ---------------------------------------------------------------------------
// Fused QKV GEMM, 2-phase double-buffered: BK=32, LDS 40KB.
// Per iter: STAGE(next buf) -> compute(cur) -> barrier.  Loads hidden.
// grid (16, 32), 512 threads; wave tile 32x32 per output matrix.
// ---------------------------------------------------------------------------
__global__ __launch_bounds__(512) void gemm_qkv(
    const bf16_t* __restrict__ A,
    const bf16_t* __restrict__ Wq, const bf16_t* __restrict__ Wk, const bf16_t* __restrict__ Wv,
    const float* __restrict__ bq, const float* __restrict__ bk, const float* __restrict__ bv,
    bf16_t* __restrict__ Cq, bf16_t* __restrict__ Ck, bf16_t* __restrict__ Cv)
{
    __shared__ __align__(16) bf16_t As[2][128 * 32];      // 2 x 8KB
    __shared__ __align__(16) bf16_t Bs[2][3 * 64 * 32];   // 2 x 12KB

    const int tid  = threadIdx.x;
    const int lane = tid & 63;
    const int w    = tid >> 6;        // 0..7
    const int wr   = w >> 1;          // 0..3: 32-row strip
    const int wc   = w & 1;           // 0..1: 32-col half
    const int bn   = blockIdx.x;      // 0..15
    const int bm   = blockIdx.y;      // 0..31

    const int l15 = lane & 15;
    const int g   = lane >> 4;

    const int srow = lane >> 2;        // 0..15 within 16-row unit
    const int scol = (lane & 3) * 8;   // 0..24

    // per-wave staging sources (wave-uniform)
    const bf16_t* aSrc  = A + (size_t)(bm * 128 + 16 * w + srow) * DIM_ + scol;
    const bf16_t* w1p   = (w < 4) ? Wq : Wk;
    const bf16_t* b1Src = w1p + (size_t)(bn * 64 + 16 * (w & 3) + srow) * DIM_ + scol;
    const bf16_t* b2Src = Wv  + (size_t)(bn * 64 + 16 * w + srow) * DIM_ + scol;  // waves 0-3 only
    const int b1Off = ((w < 4) ? 0 : 2048) + (w & 3) * 512;
    const int b2Off = 4096 + w * 512;

    f32x4 aq[2][2], ak[2][2], av[2][2];
    #pragma unroll
    for (int i = 0; i < 2; i++)
        #pragma unroll
        for (int j = 0; j < 2; j++) {
            aq[i][j] = (f32x4){0.f, 0.f, 0.f, 0.f};
            ak[i][j] = (f32x4){0.f, 0.f, 0.f, 0.f};
            av[i][j] = (f32x4){0.f, 0.f, 0.f, 0.f};
        }

    #define QSTAGE(buf, kb)                                        \
        {                                                          \
            gld16(aSrc + (kb), &As[buf][w * 512]);                 \
            gld16(b1Src + (kb), &Bs[buf][b1Off]);                  \
            if (w < 4) gld16(b2Src + (kb), &Bs[buf][b2Off]);       \
        }

    QSTAGE(0, 0);
    __syncthreads();

    for (int t = 0; t < 32; t++) {
        const int cur = t & 1;
        if (t < 31) QSTAGE(cur ^ 1, (t + 1) * 32);

        bf16x8 af[2];
        #pragma unroll
        for (int i = 0; i < 2; i++)
            af[i] = *(const bf16x8*)&As[cur][(wr * 32 + i * 16 + l15) * 32 + g * 8];
        bf16x8 bqf[2], bkf[2], bvf[2];
        #pragma unroll
        for (int j = 0; j < 2; j++) {
            const int off = (wc * 32 + j * 16 + l15) * 32 + g * 8;
            bqf[j] = *(const bf16x8*)&Bs[cur][off];
            bkf[j] = *(const bf16x8*)&Bs[cur][2048 + off];
            bvf[j] = *(const bf16x8*)&Bs[cur][4096 + off];
        }
        #pragma unroll
        for (int i = 0; i < 2; i++)
            #pragma unroll
            for (int j = 0; j < 2; j++) {
                aq[i][j] = __builtin_amdgcn_mfma_f32_16x16x32_bf16(af[i], bqf[j], aq[i][j], 0, 0, 0);
                ak[i][j] = __builtin_amdgcn_mfma_f32_16x16x32_bf16(af[i], bkf[j], ak[i][j], 0, 0, 0);
                av[i][j] = __builtin_amdgcn_mfma_f32_16x16x32_bf16(af[i], bvf[j], av[i][j], 0, 0, 0);
            }

        __syncthreads();   // drains vmcnt (next tile landed) + readers done
    }
    #undef QSTAGE

    const int r4 = g * 4;
    #pragma unroll
    for (int j = 0; j < 2; j++) {
        const int gc = bn * 64 + wc * 32 + j * 16 + l15;
        const float vq = bq[gc], vk = bk[gc], vv = bv[gc];
        #pragma unroll
        for (int i = 0; i < 2; i++) {
            #pragma unroll
            for (int r = 0; r < 4; r++) {
                const size_t gr = (size_t)(bm * 128 + wr * 32 + i * 16 + r4 + r) * DIM_ + gc;
                Cq[gr] = (bf16_t)((aq[i][j][r] + vq) * EXPC_);
                Ck[gr] = (bf16_t)(ak[i][j][r] + vk);
                Cv[gr] = (bf16_t)(av[i][j][r] + vv);
            }
        }
    }
}

// ---------------------------------------------------------------------------
// O-proj GEMM, 2-phase double-buffered: BK=64, LDS 48KB.
// grid (8, 64), 512 threads; wave tile 32x32 (2r x 4c).
// ---------------------------------------------------------------------------
__global__ __launch_bounds__(512) void gemm_o(
    const bf16_t* __restrict__ A, const bf16_t* __restrict__ Wo,
    const float* __restrict__ bo, float* __restrict__ C)
{
    __shared__ __align__(16) bf16_t As[2][64 * 64];      // 2 x 8KB
    __shared__ __align__(16) bf16_t Bs[2][128 * 64];     // 2 x 16KB

    const int tid  = threadIdx.x;
    const int lane = tid & 63;
    const int w    = tid >> 6;        // 0..7
    const int wr   = w & 1;           // 0..1
    const int wc   = w >> 1;          // 0..3
    const int bn   = blockIdx.x;      // 0..7
    const int bm   = blockIdx.y;      // 0..63

    const int l15 = lane & 15;
    const int g   = lane >> 4;

    const int srow = lane >> 3;
    const int scol = (lane & 7) * 8;

    const bf16_t* aSrc  = A  + (size_t)(bm * 64 + w * 8 + srow) * DIM_ + scol;
    const bf16_t* b0Src = Wo + (size_t)(bn * 128 + (w * 2 + 0) * 8 + srow) * DIM_ + scol;
    const bf16_t* b1Src = Wo + (size_t)(bn * 128 + (w * 2 + 1) * 8 + srow) * DIM_ + scol;

    f32x4 acc[2][2];
    #pragma unroll
    for (int i = 0; i < 2; i++)
        #pragma unroll
        for (int j = 0; j < 2; j++)
            acc[i][j] = (f32x4){0.f, 0.f, 0.f, 0.f};

    #define OSTAGE(buf, kb)                                          \
        {                                                            \
            gld16(aSrc + (kb), &As[buf][w * 512]);                   \
            gld16(b0Src + (kb), &Bs[buf][(w * 2 + 0) * 512]);        \
            gld16(b1Src + (kb), &Bs[buf][(w * 2 + 1) * 512]);        \
        }

    OSTAGE(0, 0);
    __syncthreads();

    for (int t = 0; t < 16; t++) {
        const int cur = t & 1;
        if (t < 15) OSTAGE(cur ^ 1, (t + 1) * 64);

        #pragma unroll
        for (int kk = 0; kk < 2; kk++) {
            bf16x8 af[2], bf[2];
            #pragma unroll
            for (int i = 0; i < 2; i++)
                af[i] = *(const bf16x8*)&As[cur][(wr * 32 + i * 16 + l15) * 64 + kk * 32 + g * 8];
            #pragma unroll
            for (int j = 0; j < 2; j++)
                bf[j] = *(const bf16x8*)&Bs[cur][(wc * 32 + j * 16 + l15) * 64 + kk * 32 + g * 8];
            #pragma unroll
            for (int i = 0; i < 2; i++)
                #pragma unroll
                for (int j = 0; j < 2; j++)
                    acc[i][j] = __builtin_amdgcn_mfma_f32_16x16x32_bf16(af[i], bf[j], acc[i][j], 0, 0, 0);
        }

        __syncthreads();
    }
    #undef OSTAGE

    const int r4 = g * 4;
    #pragma unroll
    for (int j = 0; j < 2; j++) {
        const int gc = bn * 128 + wc * 32 + j * 16 + l15;
        const float bv = bo[gc];
        #pragma unroll
        for (int i = 0; i < 2; i++) {
            #pragma unroll
            for (int r = 0; r < 4; r++) {
                const size_t gr = (size_t)(bm * 64 + wr * 32 + i * 16 + r4 + r) * DIM_ + gc;
                C[gr] = acc[i][j][r] + bv;
            }
        }
    }
}

// ---------------------------------------------------------------------------
// Per-head transpose: V[b][m][h*64+d] -> Vt[(b*16+h)*64 + d][m]
// ---------------------------------------------------------------------------
__global__ __launch_bounds__(256) void transpose_v(
    const bf16_t* __restrict__ V, bf16_t* __restrict__ Vt)
{
    __shared__ __align__(16) bf16_t Ts[64 * 72];
    const int tid = threadIdx.x;
    const int mt  = blockIdx.x;
    const int bh  = blockIdx.y;
    const int b   = bh >> 4, h = bh & 15;
    const int m0  = mt * 64;
    const int r   = tid >> 2;
    const int c   = (tid & 3) * 16;

    const bf16x8* s = (const bf16x8*)(V + ((size_t)(b * NN_ + m0 + r)) * DIM_ + h * HD_ + c);
    *(bf16x8*)(Ts + r * 72 + c)     = s[0];
    *(bf16x8*)(Ts + r * 72 + c + 8) = s[1];
    __syncthreads();

    bf16x8 o0, o1;
    #pragma unroll
    for (int i = 0; i < 8; i++) o0[i] = Ts[(c + i) * 72 + r];
    #pragma unroll
    for (int i = 0; i < 8; i++) o1[i] = Ts[(c + 8 + i) * 72 + r];
    bf16_t* dst = Vt + ((size_t)bh * HD_ + r) * NN_ + m0 + c;
    *(bf16x8*)dst       = o0;
    *(bf16x8*)(dst + 8) = o1;
}

// ---------------------------------------------------------------------------
// MFMA attention v9: v7 structure (verified 48.9us) minus the oL ones-MFMA;
// L as scalar per-lane VALU sum + round-10's proven merge/publish scheme.
// ---------------------------------------------------------------------------
__device__ __forceinline__ u32 cvtpk_bf16(float lo, float hi) {
    u32 d;
    asm volatile("v_cvt_pk_bf16_f32 %0, %1, %2" : "=v"(d) : "v"(lo), "v"(hi));
    return d;
}

__global__ __launch_bounds__(512, 4) void attn_mfma9(
    const bf16_t* __restrict__ Qa,   // kb (attention-query rows n)
    const bf16_t* __restrict__ Ka,   // qb (attention-key rows m, pre-scaled by EXPC_)
    const bf16_t* __restrict__ Vtg,  // V^T per head [bh][d][m]
    bf16_t* __restrict__ O)
{
    __shared__ __align__(16) bf16_t Kt[2][128 * 72];   // 36.9 KB
    __shared__ __align__(16) bf16_t Vt[2][64 * 136];   // 34.8 KB

    const int tid  = threadIdx.x;
    const int lane = tid & 63;
    const int w    = tid >> 6;       // 0..7
    const int l31  = lane & 31;
    const int h5   = lane >> 5;

    const int nw = (w & 3) * 32;     // wave's n-offset in block
    const int mo = (w >> 2) * 64;    // wave's m-half within each 128-m tile

    const int wg = blockIdx.x;
    const int id = (wg & 7) * 64 + (wg >> 3);
    const int bh = id >> 4;          // 0..31
    const int nt = id & 15;          // 0..15
    const int b  = bh >> 4, h = bh & 15;
    const int n0 = nt * 128;

    const size_t base = (size_t)b * NN_ * DIM_ + h * HD_;

    const bf16_t* qrow = Qa + base + (size_t)(n0 + nw + l31) * DIM_ + h5 * 8;
    bf16x8 qf[4];
    #pragma unroll
    for (int ks = 0; ks < 4; ks++)
        qf[ks] = *(const bf16x8*)(qrow + ks * 16);

    f32x16 oa0 = {}, oa1 = {};
    float Lp = 0.f;

    const bf16_t* vrow   = Vtg + (size_t)bh * HD_ * NN_;
    const bf16_t* kgbase = Ka + base;

    const int kr2 = tid >> 3;          // 0..63
    const int kc2 = (tid & 7) * 8;     // K d-col: 0..56
    const int vc2 = (tid & 7) * 16;    // V m-col: 0..112

    bf16x8 kA0, kB0, vA0, vA1;

    #define ISSUE(m0)                                                                        \
        {                                                                                    \
            kA0 = *(const bf16x8*)(kgbase + (size_t)((m0) + kr2) * DIM_ + kc2);              \
            kB0 = *(const bf16x8*)(kgbase + (size_t)((m0) + 64 + kr2) * DIM_ + kc2);         \
            const bf16x8* vp = (const bf16x8*)(vrow + (size_t)kr2 * NN_ + (m0) + vc2);       \
            vA0 = vp[0]; vA1 = vp[1];                                                        \
        }
    #define COMMIT(buf)                                                                      \
        {                                                                                    \
            *(bf16x8*)(Kt[buf] + kr2 * 72 + kc2)        = kA0;                               \
            *(bf16x8*)(Kt[buf] + (64 + kr2) * 72 + kc2) = kB0;                               \
            bf16_t* vd = Vt[buf] + kr2 * 136 + vc2;                                          \
            *(bf16x8*)(vd)     = vA0;                                                        \
            *(bf16x8*)(vd + 8) = vA1;                                                        \
        }

    ISSUE(0);
    COMMIT(0);
    __syncthreads();

    for (int mt = 0; mt < NN_ / 128; mt++) {
        const int cur = mt & 1;
        if (mt < NN_ / 128 - 1) ISSUE((mt + 1) * 128);

        const bf16_t* KtC = Kt[cur];
        const bf16_t* VtC = Vt[cur];

        f32x16 sa0 = {}, sa1 = {};
        __builtin_amdgcn_s_setprio(1);
        #pragma unroll
        for (int ks = 0; ks < 4; ks++) {
            bf16x8 kf0 = *(const bf16x8*)&KtC[(mo + l31) * 72 + ks * 16 + h5 * 8];
            bf16x8 kf1 = *(const bf16x8*)&KtC[(mo + 32 + l31) * 72 + ks * 16 + h5 * 8];
            sa0 = __builtin_amdgcn_mfma_f32_32x32x16_bf16(kf0, qf[ks], sa0, 0, 0, 0);
            sa1 = __builtin_amdgcn_mfma_f32_32x32x16_bf16(kf1, qf[ks], sa1, 0, 0, 0);
        }
        __builtin_amdgcn_s_setprio(0);

        // P = exp2(S^T) via hw v_exp_f32; scalar per-lane L (all p same n)
        float p0[16], p1[16];
        #pragma unroll
        for (int r = 0; r < 16; r++) { p0[r] = exp2_hw(sa0[r]); p1[r] = exp2_hw(sa1[r]); }
        {
            float s0 = (p0[0] + p0[1]) + (p0[2] + p0[3]);
            float s1 = (p0[4] + p0[5]) + (p0[6] + p0[7]);
            float s2 = (p0[8] + p0[9]) + (p0[10] + p0[11]);
            float s3 = (p0[12] + p0[13]) + (p0[14] + p0[15]);
            float t0 = (p1[0] + p1[1]) + (p1[2] + p1[3]);
            float t1 = (p1[4] + p1[5]) + (p1[6] + p1[7]);
            float t2 = (p1[8] + p1[9]) + (p1[10] + p1[11]);
            float t3 = (p1[12] + p1[13]) + (p1[14] + p1[15]);
            Lp += ((s0 + s1) + (s2 + s3)) + ((t0 + t1) + (t2 + t3));
        }

        bf16x8 pf[4];
        #pragma unroll
        for (int mb = 0; mb < 4; mb++) {
            const float* pp = (mb & 2) ? p1 : p0;
            const int rb = (mb & 1) * 8;
            u32 x0 = cvtpk_bf16(pp[rb + 0], pp[rb + 1]);
            u32 x1 = cvtpk_bf16(pp[rb + 2], pp[rb + 3]);
            u32 y0 = cvtpk_bf16(pp[rb + 4], pp[rb + 5]);
            u32 y1 = cvtpk_bf16(pp[rb + 6], pp[rb + 7]);
            asm volatile("v_permlane32_swap_b32 %0, %1" : "+v"(x0), "+v"(y0));
            asm volatile("v_permlane32_swap_b32 %0, %1" : "+v"(x1), "+v"(y1));
            u32x4 t; t.x = x0; t.y = x1; t.z = y0; t.w = y1;
            pf[mb] = __builtin_bit_cast(bf16x8, t);
        }

        __builtin_amdgcn_s_setprio(1);
        #pragma unroll
        for (int ms = 0; ms < 4; ms++) {
            bf16x8 vf0 = *(const bf16x8*)&VtC[l31 * 136 + mo + ms * 16 + h5 * 8];
            bf16x8 vf1 = *(const bf16x8*)&VtC[(32 + l31) * 136 + mo + ms * 16 + h5 * 8];
            oa0 = __builtin_amdgcn_mfma_f32_32x32x16_bf16(pf[ms], vf0, oa0, 0, 0, 0);
            oa1 = __builtin_amdgcn_mfma_f32_32x32x16_bf16(pf[ms], vf1, oa1, 0, 0, 0);
        }
        __builtin_amdgcn_s_setprio(0);

        if (mt < NN_ / 128 - 1) COMMIT(cur ^ 1);
        __syncthreads();
    }
    #undef ISSUE
    #undef COMMIT

    // lane + h5-partner cover the wave's full 64-m slice per n
    Lp += __shfl_xor(Lp, 32);

    // merge m-half partials: waves 4-7 write (oa0|oa1|L) slots, waves 0-3 add.
    // slot s: 2112 floats = oa0 1024 | oa1 1024 | L 64.
    float* scratch0 = (float*)Kt;   // 9216 floats available
    float* scratch1 = (float*)Vt;   // 8704 floats available
    if (w >= 4) {
        float* buf = (w < 6) ? (scratch0 + (w - 4) * 2112)
                             : (scratch1 + (w - 6) * 2112);
        #pragma unroll
        for (int reg = 0; reg < 16; reg++) {
            buf[reg * 64 + lane]        = oa0[reg];
            buf[1024 + reg * 64 + lane] = oa1[reg];
        }
        buf[2048 + lane] = Lp;
    }
    __syncthreads();
    if (w < 4) {
        const float* buf = (w < 2) ? (scratch0 + w * 2112)
                                   : (scratch1 + (w - 2) * 2112);
        #pragma unroll
        for (int reg = 0; reg < 16; reg++) {
            oa0[reg] += buf[reg * 64 + lane];
            oa1[reg] += buf[1024 + reg * 64 + lane];
        }
        Lp += buf[2048 + lane];
    }
    __syncthreads();

    // publish L[n] (lane holds L for n = nw + l31), then epilogue
    float* Lsh = scratch0 + 4224;   // floats 4224..4351, past both scratch0 slots
    if (w < 4) Lsh[nw + l31] = Lp;
    __syncthreads();

    if (w < 4) {
        #pragma unroll
        for (int reg = 0; reg < 16; reg++) {
            const int nr = (reg & 3) + 8 * (reg >> 2) + 4 * h5;
            const float il = 1.f / Lsh[nw + nr];
            const size_t rowoff = base + (size_t)(n0 + nw + nr) * DIM_;
            O[rowoff + l31]      = (bf16_t)(oa0[reg] * il);
            O[rowoff + 32 + l31] = (bf16_t)(oa1[reg] * il);
        }
    }
}

// ---------------------------------------------------------------------------
extern "C" void kernel_launch(void* const* d_in, const int* in_sizes, int n_in,
                              void* d_out, int out_size, void* d_ws, size_t ws_size,
                              hipStream_t stream)
{
    const float* x  = (const float*)d_in[0];
    const float* Wq = (const float*)d_in[1];
    const float* bq = (const float*)d_in[2];
    const float* Wk = (const float*)d_in[3];
    const float* bk = (const float*)d_in[4];
    const float* Wv = (const float*)d_in[5];
    const float* bv = (const float*)d_in[6];
    const float* Wo = (const float*)d_in[7];
    const float* bo = (const float*)d_in[8];
    float* out = (float*)d_out;

    const size_t SEG = (size_t)MTOT * DIM_;   // 4M elems = 8MB bf16
    bf16_t* xb = (bf16_t*)d_ws;
    bf16_t* qb = xb + SEG;
    bf16_t* kb = qb + SEG;
    bf16_t* vb = kb + SEG;
    bf16_t* vt = xb;   // xb dead after QKV gemm
    bf16_t* ab = vb;   // vb dead after transpose

    // bf16 weights in [32MB, 40MB)
    bf16_t* wqb = vb + SEG;
    bf16_t* wkb = wqb + (size_t)DIM_ * DIM_;
    bf16_t* wvb = wkb + (size_t)DIM_ * DIM_;
    bf16_t* wob = wvb + (size_t)DIM_ * DIM_;

    cvt_all<<<dim3(4096), 256, 0, stream>>>(x, Wq, Wk, Wv, Wo, xb, wqb, wkb, wvb, wob);

    gemm_qkv<<<dim3(16, 32), 512, 0, stream>>>(
        xb, wqb, wkb, wvb, bq, bk, bv, qb, kb, vb);

    dim3 gt(NN_ / 64, BB_ * HEADS_);
    transpose_v<<<gt, 256, 0, stream>>>(vb, vt);

    attn_mfma9<<<dim3(512), 512, 0, stream>>>(kb, qb, vt, ab);

    gemm_o<<<dim3(8, 64), 512, 0, stream>>>(ab, wob, bo, out);
}